// Round 13
// baseline (119.263 us; speedup 1.0000x reference)
//
#include <hip/hip_runtime.h>
#include <math.h>

// Adder2D: out[n,co,h,w] = -sum_{ci,kh,kw} |x[n,ci,h+kh-1,w+kw-1] - w[co,ci,kh,kw]|
// x: [16,64,32,32] f32, w: [64,64,3,3] f32, out: [16,64,32,32] f32, pad=1 stride=1.
//
// R13b: NO LDS, NO BARRIERS -- workspace-safe variant. R13 (padded-x copy)
// needed 5.3MB of d_ws and died twice at container level, likely OOB
// workspace write (all successful rounds used only 256KB). Same theory,
// safe implementation: halo handled by clamped global addresses + cndmask
// zeroing instead of a padded copy.
//   - R4-R12 ledger: six w-feed/occupancy variants all 47-57us; no pipe
//     >40% busy; conflicts 0; SMEM drains 4x fewer -> no change. Invariant
//     wall = stage->drain->barrier->compute convoy (compiler must emit
//     vmcnt(0)+lgkmcnt(0) before every s_barrier). x is 4MB = L2-resident:
//     LDS-staging it is guide Common-mistake #7.
//   - thread = 2px x 4co x ALL 64 ci (no ci-split, no reduction). 2048
//     waves = 8/CU. Zero barriers: waves run free, loads pipeline.
//   - per ci: 9 VMEM (aligned dwordx2 + 2 clamped dwords per row, L1/L2
//     hit) + ~10 cndmask (edge zeros) + 144 core VALU.
//   - w: batched 72-float s_load per 2 ci (uniform ptr, 256KB repack ws).
//     lgkmcnt is SMEM-pure here; nothing to drain, no barrier vmcnt(0).

#define N_   16
#define CI_  64
#define CO_  64
#define HW_  32
#define CG   4
#define WSLICE 64                     // floats per (coq,ci) w slot

// ---- repack: w[co][ci][t] -> wr[(co/4)*64+ci][(co&3)*9+t], 64-f slots ----
__global__ void repack_w(const float* __restrict__ w, float* __restrict__ wr)
{
    int i  = blockIdx.x * 256 + threadIdx.x;   // 4096 (co,ci) pairs
    int co = i >> 6;
    int ci = i & 63;
    float* dst = wr + (size_t)((co >> 2) * 64 + ci) * WSLICE + (co & 3) * 9;
    const float* src = w + (size_t)co * (CI_ * 9) + ci * 9;
#pragma unroll
    for (int t = 0; t < 9; ++t) dst[t] = src[t];
}

__global__ __launch_bounds__(256) void adder2d_kernel(
    const float* __restrict__ x, const float* __restrict__ wr,
    float* __restrict__ out)
{
    const int tid = threadIdx.x;
    const int u   = tid & 15;            // col-pair: output cols 2u, 2u+1
    const int rl  = tid >> 4;            // 0..15
    const int r   = blockIdx.x * 16 + rl;
    const int coq = blockIdx.y;          // co quad 0..15
    const int n   = blockIdx.z;

    // halo handling: clamped offsets (never OOB) + zero masks
    const bool rv0 = (r >= 1), rv2 = (r <= 30);       // rows r-1, r+1 valid
    const bool lv  = (u > 0),  rv  = (u < 15);        // left/right col valid
    const int  ro0 = rv0 ? (r - 1) : 0;               // clamped row indices
    const int  ro2 = rv2 ? (r + 1) : 31;
    const int  cl  = lv ? (2 * u - 1) : 0;            // clamped col indices
    const int  cr  = rv ? (2 * u + 2) : 31;

    const float* xb = x + (size_t)(n * CI_) * (HW_ * HW_);
    const float* wb = wr + (size_t)coq * 64 * WSLICE; // uniform -> s_load path

    float acc0[CG] = {0.f, 0.f, 0.f, 0.f};
    float acc1[CG] = {0.f, 0.f, 0.f, 0.f};

#define LOAD_ROW(KH, ROWIDX, ROWOK)                                           \
        {                                                                     \
            const float* rowp = xc + (ROWIDX) * HW_;                          \
            float2 m = *(const float2*)(rowp + 2 * u);                        \
            float  l = rowp[cl];                                              \
            float  rr = rowp[cr];                                             \
            win[KH][0] = ((ROWOK) && lv) ? l    : 0.f;                        \
            win[KH][1] = (ROWOK)         ? m.x  : 0.f;                        \
            win[KH][2] = (ROWOK)         ? m.y  : 0.f;                        \
            win[KH][3] = ((ROWOK) && rv) ? rr   : 0.f;                        \
        }

#define COMPUTE_CI(CIV, WU)                                                   \
    {                                                                         \
        const float* xc = xb + (size_t)(CIV) * (HW_ * HW_);                   \
        float win[3][4];                                                      \
        LOAD_ROW(0, ro0, rv0)                                                 \
        LOAD_ROW(1, r,   true)                                                \
        LOAD_ROW(2, ro2, rv2)                                                 \
        _Pragma("unroll")                                                     \
        for (int kh = 0; kh < 3; ++kh)                                        \
            _Pragma("unroll")                                                 \
            for (int kw = 0; kw < 3; ++kw) {                                  \
                const int t = kh * 3 + kw;                                    \
                float xa = win[kh][kw];                                       \
                float xb2 = win[kh][kw + 1];                                  \
                _Pragma("unroll")                                             \
                for (int j = 0; j < CG; ++j) {                                \
                    const float wjt = WU[j * 9 + t];                          \
                    acc0[j] += fabsf(xa - wjt);                               \
                    acc1[j] += fabsf(xb2 - wjt);                              \
                }                                                             \
            }                                                                 \
    }

    for (int ci = 0; ci < CI_; ci += 2) {
        // one batched 72-float scalar load per 2 ci (uniform pointer ->
        // s_load; SMEM-pure lgkmcnt, nothing else to drain)
        const float* wp = wb + (size_t)ci * WSLICE;
        float wA[36], wB[36];
#pragma unroll
        for (int t = 0; t < 36; ++t) wA[t] = wp[t];
#pragma unroll
        for (int t = 0; t < 36; ++t) wB[t] = wp[WSLICE + t];

        COMPUTE_CI(ci,     wA)
        COMPUTE_CI(ci + 1, wB)
    }
#undef COMPUTE_CI
#undef LOAD_ROW

    float* op = out + (((size_t)n * CO_ + coq * CG) * HW_ + r) * HW_ + 2 * u;
#pragma unroll
    for (int j = 0; j < CG; ++j)
        *(float2*)&op[(size_t)j * HW_ * HW_] = float2{-acc0[j], -acc1[j]};
}

extern "C" void kernel_launch(void* const* d_in, const int* in_sizes, int n_in,
                              void* d_out, int out_size, void* d_ws, size_t ws_size,
                              hipStream_t stream) {
    const float* x  = (const float*)d_in[0];
    const float* wp = (const float*)d_in[1];
    float* out      = (float*)d_out;
    float* wr       = (float*)d_ws;   // 256 KiB only (proven-safe footprint)

    repack_w<<<dim3(16), 256, 0, stream>>>(wp, wr);
    dim3 grid(2, 16, 16);   // (row-groups, co-quads, n) = 512 blocks x 256 thr
    adder2d_kernel<<<grid, 256, 0, stream>>>(x, wr, out);
}

// Round 14
// 103.736 us; speedup vs baseline: 1.1497x; 1.1497x over previous
//
#include <hip/hip_runtime.h>
#include <math.h>

// Adder2D: out[n,co,h,w] = -sum_{ci,kh,kw} |x[n,ci,h+kh-1,w+kw-1] - w[co,ci,kh,kw]|
// x: [16,64,32,32] f32, w: [64,64,3,3] f32, out: [16,64,32,32] f32, pad=1 stride=1.
//
// R14: make the no-LDS pipeline REAL. R13b regressed (68us) with VGPR=36:
// launch_bounds(256) let the allocator chase occupancy the 2048-wave grid
// can't use (2 waves/SIMD resident), so nothing was prefetched and every ci
// exposed ~250cy L2 latency against 288cy compute. Fix:
//   1) __launch_bounds__(256, 2): tell the allocator the true residency ->
//      VGPR cap 256, room for load buffers.
//   2) Explicit 2-deep software pipeline: named A/B buffers (no runtime
//      indexing), body = issue B(ci+1) -> s_load w -> compute A(ci) ->
//      issue A(ci+2) -> compute B(ci+1). Raw clamped-address loads; halo
//      masks applied at COMPUTE time so loads never force an early wait.
//      #pragma unroll 1 keeps the body ~2.5KB; vmcnt counting carries the
//      pipeline across iterations.
// w feed: proven SMEM path (72-float batch / 2 ci, uniform ptr; lgkmcnt is
// SMEM-pure -- zero DS ops in this kernel). Zero LDS, zero barriers.

#define N_   16
#define CI_  64
#define CO_  64
#define HW_  32
#define CG   4
#define WSLICE 64                     // floats per (coq,ci) w slot

// ---- repack: w[co][ci][t] -> wr[(co/4)*64+ci][(co&3)*9+t], 64-f slots ----
__global__ void repack_w(const float* __restrict__ w, float* __restrict__ wr)
{
    int i  = blockIdx.x * 256 + threadIdx.x;   // 4096 (co,ci) pairs
    int co = i >> 6;
    int ci = i & 63;
    float* dst = wr + (size_t)((co >> 2) * 64 + ci) * WSLICE + (co & 3) * 9;
    const float* src = w + (size_t)co * (CI_ * 9) + ci * 9;
#pragma unroll
    for (int t = 0; t < 9; ++t) dst[t] = src[t];
}

__global__ __launch_bounds__(256, 2) void adder2d_kernel(
    const float* __restrict__ x, const float* __restrict__ wr,
    float* __restrict__ out)
{
    const int tid = threadIdx.x;
    const int u   = tid & 15;            // col-pair: output cols 2u, 2u+1
    const int rl  = tid >> 4;            // 0..15
    const int r   = blockIdx.x * 16 + rl;
    const int coq = blockIdx.y;          // co quad 0..15
    const int n   = blockIdx.z;

    // clamped (always in-bounds) addresses; zero-masks applied at compute
    const bool rv0 = (r >= 1), rv2 = (r <= 30);
    const bool lv  = (u > 0),  rv  = (u < 15);
    const int  ro0 = rv0 ? (r - 1) : r;
    const int  ro2 = rv2 ? (r + 1) : r;
    const int  cl  = lv ? (2 * u - 1) : (2 * u);
    const int  cr  = rv ? (2 * u + 2) : (2 * u);

    const float* xb = x + (size_t)(n * CI_) * (HW_ * HW_);
    const float* wb = wr + (size_t)coq * 64 * WSLICE;   // uniform -> s_load

    float acc0[CG] = {0.f, 0.f, 0.f, 0.f};
    float acc1[CG] = {0.f, 0.f, 0.f, 0.f};

    float A[3][4], B[3][4];   // raw (unmasked) x windows, 2 ci in flight

#define XLOAD(BUF, CIV)                                                       \
    {                                                                         \
        const float* xc = xb + (size_t)(CIV) * (HW_ * HW_);                   \
        _Pragma("unroll")                                                     \
        for (int kh = 0; kh < 3; ++kh) {                                      \
            const int ridx = (kh == 0) ? ro0 : ((kh == 1) ? r : ro2);         \
            const float* rowp = xc + ridx * HW_;                              \
            float2 m = *(const float2*)(rowp + 2 * u);                        \
            BUF[kh][0] = rowp[cl];  BUF[kh][1] = m.x;                         \
            BUF[kh][2] = m.y;       BUF[kh][3] = rowp[cr];                    \
        }                                                                     \
    }

#define XCOMP(BUF, WU)                                                        \
    {                                                                         \
        float win[3][4];                                                      \
        win[0][0] = (rv0 && lv) ? BUF[0][0] : 0.f;                            \
        win[0][1] = rv0 ? BUF[0][1] : 0.f;                                    \
        win[0][2] = rv0 ? BUF[0][2] : 0.f;                                    \
        win[0][3] = (rv0 && rv) ? BUF[0][3] : 0.f;                            \
        win[1][0] = lv ? BUF[1][0] : 0.f;                                     \
        win[1][1] = BUF[1][1];                                                \
        win[1][2] = BUF[1][2];                                                \
        win[1][3] = rv ? BUF[1][3] : 0.f;                                     \
        win[2][0] = (rv2 && lv) ? BUF[2][0] : 0.f;                            \
        win[2][1] = rv2 ? BUF[2][1] : 0.f;                                    \
        win[2][2] = rv2 ? BUF[2][2] : 0.f;                                    \
        win[2][3] = (rv2 && rv) ? BUF[2][3] : 0.f;                            \
        _Pragma("unroll")                                                     \
        for (int kh = 0; kh < 3; ++kh)                                        \
            _Pragma("unroll")                                                 \
            for (int kw = 0; kw < 3; ++kw) {                                  \
                const int t = kh * 3 + kw;                                    \
                float xa  = win[kh][kw];                                      \
                float xb2 = win[kh][kw + 1];                                  \
                _Pragma("unroll")                                             \
                for (int j = 0; j < CG; ++j) {                                \
                    const float wjt = WU[j * 9 + t];                          \
                    acc0[j] += fabsf(xa - wjt);                               \
                    acc1[j] += fabsf(xb2 - wjt);                              \
                }                                                             \
            }                                                                 \
    }

    XLOAD(A, 0)
#pragma unroll 1
    for (int ci = 0; ci < CI_; ci += 2) {
        XLOAD(B, ci + 1)                      // issue next-ci loads (vmcnt)
        const float* wp = wb + (size_t)ci * WSLICE;
        float wA[36], wB[36];
#pragma unroll
        for (int t = 0; t < 36; ++t) wA[t] = wp[t];
#pragma unroll
        for (int t = 0; t < 36; ++t) wB[t] = wp[WSLICE + t];

        XCOMP(A, wA)                          // consume A while B in flight
        const int cn = (ci + 2 < CI_) ? (ci + 2) : 0;  // harmless tail reload
        XLOAD(A, cn)                          // issue ci+2 loads
        XCOMP(B, wB)                          // consume B while A in flight
    }
#undef XLOAD
#undef XCOMP

    float* op = out + (((size_t)n * CO_ + coq * CG) * HW_ + r) * HW_ + 2 * u;
#pragma unroll
    for (int j = 0; j < CG; ++j)
        *(float2*)&op[(size_t)j * HW_ * HW_] = float2{-acc0[j], -acc1[j]};
}

extern "C" void kernel_launch(void* const* d_in, const int* in_sizes, int n_in,
                              void* d_out, int out_size, void* d_ws, size_t ws_size,
                              hipStream_t stream) {
    const float* x  = (const float*)d_in[0];
    const float* wp = (const float*)d_in[1];
    float* out      = (float*)d_out;
    float* wr       = (float*)d_ws;   // 256 KiB (proven-safe footprint)

    repack_w<<<dim3(16), 256, 0, stream>>>(wp, wr);
    dim3 grid(2, 16, 16);   // (row-groups, co-quads, n) = 512 blocks x 256 thr
    adder2d_kernel<<<grid, 256, 0, stream>>>(x, wr, out);
}

// Round 15
// 97.284 us; speedup vs baseline: 1.2259x; 1.0663x over previous
//
#include <hip/hip_runtime.h>
#include <math.h>

// Adder2D: out[n,co,h,w] = -sum_{ci,kh,kw} |x[n,ci,h+kh-1,w+kw-1] - w[co,ci,kh,kw]|
// x: [16,64,32,32] f32, w: [64,64,3,3] f32, out: [16,64,32,32] f32, pad=1 stride=1.
//
// R15: packed FP32 core (VOP3P). Model audit: instruction-count-derived
// VALU busy (~42%) vs derived counter (70%) implies the emitted VALU count
// is ~1.5-2x the source-level model (abs likely not always fused) and the
// counter is ~face-value: best kernels are ~70% VALU-ISSUE-bound. Six
// structural variants (LDS/no-LDS, barriers/none, 2-32 waves/CU, w on
// LDS/VMEM/SMEM) all land 47-57us because they all optimized the ~30%
// stall share, not the ~70% VALU share. gfx950 fp32 peak (157 TF) needs
// v_pk_*_f32 -- scalar caps at 78.6. Now: pack across the 2-pixel dim:
//   - f2 accumulators (aligned VGPR pairs)
//   - window as 3 overlapping f2 per row from b32 reads (ds_read2_b32
//     writes an aligned pair; overlap handled by CSE)
//   - w splat from SGPR into both halves (op_sel, free)
//   - core = pk_sub + packed-abs + pk_add = 3 instr / 2 elems, vs 4-6.
// Host structure is R11 VERBATIM (47.7us best: 512thr, 4-way cig split,
// LW=35 conflict-free, readfirstlane s_load w, LDS reduction).

#define N_   16
#define CI_  64
#define CO_  64
#define HW_  32
#define CG   4      // co per thread (= all of COB)
#define COB  4      // co per block
#define RG   8      // pixel rows per block
#define CIC  16     // ci planes staged per round
#define CPG  4      // ci planes computed per group per round
#define ROWS (RG + 2)
#define LW   35     // word0 = left halo, 1..32 = data, 33 = right halo, 34 pad
#define WSLICE 64   // floats per (cob,ci) w-slice slot (36 used, 256B aligned)

#define XS_WORDS (CIC * ROWS * LW)        // 5600 words = 22400 B

typedef __attribute__((ext_vector_type(2))) float f2;

// ---- repack: w[co][ci][t] -> wr[(co/4)*64+ci][ (co&3)*9 + t ], 64-f slots ----
__global__ void repack_w(const float* __restrict__ w, float* __restrict__ wr)
{
    int i  = blockIdx.x * 256 + threadIdx.x;   // 4096 = (co,ci) pairs
    int co = i >> 6;
    int ci = i & 63;
    float* dst = wr + (size_t)((co >> 2) * 64 + ci) * WSLICE + (co & 3) * 9;
    const float* src = w + (size_t)co * (CI_ * 9) + ci * 9;
#pragma unroll
    for (int t = 0; t < 9; ++t) dst[t] = src[t];
}

__global__ __launch_bounds__(512, 4) void adder2d_kernel(
    const float* __restrict__ x, const float* __restrict__ wr,
    float* __restrict__ out)
{
    __shared__ __align__(16) float smem[XS_WORDS];
    float (*xs)[ROWS][LW] = (float (*)[ROWS][LW])smem;   // phase A
    float (*red)[128][8]  = (float (*)[128][8])smem;     // phase B: aliases xs
                                                         // 3*128*8 = 3072 <= 5600 ok

    const int tid = threadIdx.x;
    const int u   = tid & 15;            // col-pair: pixels at cols 2u, 2u+1
    const int rl  = (tid >> 4) & 7;      // pixel row within block
    const int cig = tid >> 7;            // ci group: 0..3 (uniform per wave)
    const int r0  = blockIdx.x * RG;
    const int co0 = blockIdx.y * COB;
    const int n   = blockIdx.z;

    // wave-uniform group index -> provably scalar w pointer (s_load path)
    const int cigs = __builtin_amdgcn_readfirstlane(cig);
    const float* wrb = wr + (size_t)blockIdx.y * 64 * WSLICE;

    // ---- zero xs once: halo words (0,33) and OOB row slots stay zero ----
    for (int i = tid; i < XS_WORDS / 4; i += 512)
        ((float4*)smem)[i] = float4{0.f, 0.f, 0.f, 0.f};

    f2 acc2[CG];                         // .x = pixel col 2u, .y = col 2u+1
#pragma unroll
    for (int j = 0; j < CG; ++j) acc2[j] = f2{0.f, 0.f};

    const float* xn = x + (size_t)n * CI_ * HW_ * HW_;
    const int pbase = cig * CPG;

    for (int round = 0; round < CI_ / CIC; ++round) {
        const int cc0 = round * CIC;
        __syncthreads();   // protect LDS from previous round's readers
        // ---- stage CIC planes, rows r0-1..r0+8: 1280 float4 units ----
        for (int i = tid; i < CIC * ROWS * (HW_ / 4); i += 512) {
            int plane = i / (ROWS * (HW_ / 4));
            int rem   = i - plane * (ROWS * (HW_ / 4));
            int rr    = rem >> 3;
            int f4    = rem & 7;
            int gr    = r0 - 1 + rr;
            if ((unsigned)gr < HW_) {
                float4 v = ((const float4*)(xn + (size_t)(cc0 + plane) * HW_ * HW_
                                            + gr * HW_))[f4];
                float* dst = &xs[plane][rr][1 + 4 * f4];   // data words 1..32
                dst[0] = v.x; dst[1] = v.y; dst[2] = v.z; dst[3] = v.w;
            }
        }
        __syncthreads();

#pragma unroll
        for (int cil = 0; cil < CPG; ++cil) {
            const int pl  = pbase + cil;             // per-thread (LDS path)
            const int cis = cc0 + cigs * CPG + cil;  // uniform (SMEM path)

            // ---- w slice: plain loads from uniform pointer -> s_load ----
            const float* wu_p = wrb + (size_t)cis * WSLICE;
            float wu[36];
#pragma unroll
            for (int t = 0; t < 36; ++t) wu[t] = wu_p[t];

            // x window: 3 overlapping f2 pairs per row (ds_read2_b32-
            // friendly; pairs land in aligned VGPR pairs for VOP3P)
            f2 xp[3][3];
#pragma unroll
            for (int kh = 0; kh < 3; ++kh) {
                const float* row = &xs[pl][rl + kh][2 * u];
                float a = row[0], b = row[1], c = row[2], d = row[3];
                xp[kh][0] = f2{a, b};
                xp[kh][1] = f2{b, c};
                xp[kh][2] = f2{c, d};
            }

            // packed core: 9 taps x 4 co x {pk_sub, packed-abs, pk_add}
#pragma unroll
            for (int kh = 0; kh < 3; ++kh)
#pragma unroll
                for (int kw = 0; kw < 3; ++kw) {
                    const int t = kh * 3 + kw;
#pragma unroll
                    for (int j = 0; j < CG; ++j) {
                        const float wjt = wu[j * 9 + t];
                        f2 dv = xp[kh][kw] - f2{wjt, wjt};
                        acc2[j] += __builtin_elementwise_abs(dv);
                    }
                }
        }
    }

    // ---- combine the four ci-group partials (red aliases dead xs) ----
    __syncthreads();   // all xs readers done before overwrite
    if (cig != 0) {
        int t = tid & 127;
        *(float4*)&red[cig - 1][t][0] =
            float4{acc2[0].x, acc2[1].x, acc2[2].x, acc2[3].x};
        *(float4*)&red[cig - 1][t][4] =
            float4{acc2[0].y, acc2[1].y, acc2[2].y, acc2[3].y};
    }
    __syncthreads();
    if (cig == 0) {
        float acc0[CG] = {acc2[0].x, acc2[1].x, acc2[2].x, acc2[3].x};
        float acc1[CG] = {acc2[0].y, acc2[1].y, acc2[2].y, acc2[3].y};
#pragma unroll
        for (int g = 0; g < 3; ++g) {
            float4 ra = *(const float4*)&red[g][tid][0];
            float4 rb = *(const float4*)&red[g][tid][4];
            acc0[0] += ra.x; acc0[1] += ra.y; acc0[2] += ra.z; acc0[3] += ra.w;
            acc1[0] += rb.x; acc1[1] += rb.y; acc1[2] += rb.z; acc1[3] += rb.w;
        }
        float* op = out + (((size_t)n * CO_ + co0) * HW_ + (r0 + rl)) * HW_ + 2 * u;
#pragma unroll
        for (int j = 0; j < CG; ++j)
            *(float2*)&op[(size_t)j * HW_ * HW_] = float2{-acc0[j], -acc1[j]};
    }
}

extern "C" void kernel_launch(void* const* d_in, const int* in_sizes, int n_in,
                              void* d_out, int out_size, void* d_ws, size_t ws_size,
                              hipStream_t stream) {
    const float* x  = (const float*)d_in[0];
    const float* wp = (const float*)d_in[1];
    float* out      = (float*)d_out;
    float* wr       = (float*)d_ws;   // 256 KiB (proven-safe footprint)

    repack_w<<<dim3(16), 256, 0, stream>>>(wp, wr);
    dim3 grid(HW_ / RG, CO_ / COB, N_);   // (4, 16, 16) = 1024 blocks
    adder2d_kernel<<<grid, 512, 0, stream>>>(x, wr, out);
}

// Round 16
// 96.101 us; speedup vs baseline: 1.2410x; 1.0123x over previous
//
#include <hip/hip_runtime.h>
#include <math.h>

// Adder2D: out[n,co,h,w] = -sum_{ci,kh,kw} |x[n,ci,h+kh-1,w+kw-1] - w[co,ci,kh,kw]|
// x: [16,64,32,32] f32, w: [64,64,3,3] f32, out: [16,64,32,32] f32, pad=1 stride=1.
//
// R16: amortize per-ci latency across CO. R15 post-mortem: VGPR=28 (zero
// prefetch depth), true VALU ~31% (70% counter = 2.26x gfx94x inflation),
// core already at the VOP3P floor (pk_add(neg) + 2x v_add(abs) = 3 instr
// per 2 taps; VOP3P has no abs modifier). Eleven variants pinned at ~47us:
// stall-dominated by PER-CI latency events (ds_read chain + s_load wait)
// paid every ~108 core VALU. The px-axis amortization (R9) failed because
// it doubled VMEM+VGPR; the co axis reuses the SAME window: CG 4->8 means
// 12 ds_reads + 1 s_load batch feed 216 core VALU (4.5:1 -> 9:1).
// Block 512 thr = 128 output-threads x 4 ci-groups, COB=8, grid (4,8,16)
// = 512 blocks, 2/CU. w repacked per co-OCTET (72 floats, WSLICE=128).
// All else = R15 (LW=35 conflict-free, readfirstlane s_load, f2 core).

#define N_   16
#define CI_  64
#define CO_  64
#define HW_  32
#define CG   8      // co per thread (= all of COB)
#define COB  8      // co per block
#define RG   8      // pixel rows per block
#define CIC  16     // ci planes staged per round
#define CPG  4      // ci planes computed per group per round
#define ROWS (RG + 2)
#define LW   35     // word0 = left halo, 1..32 = data, 33 = right halo, 34 pad
#define WSLICE 128  // floats per (co-octet,ci) w slot (72 used, 512B aligned)

#define XS_WORDS (CIC * ROWS * LW)        // 5600 words = 22400 B
#define RED_WORDS (3 * 128 * 16)          // 6144 words = 24576 B
#define SMEM_WORDS (RED_WORDS > XS_WORDS ? RED_WORDS : XS_WORDS)

typedef __attribute__((ext_vector_type(2))) float f2;

// ---- repack: w[co][ci][t] -> wr[(co/8)*64+ci][ (co&7)*9 + t ], 128-f slots ----
__global__ void repack_w(const float* __restrict__ w, float* __restrict__ wr)
{
    int i  = blockIdx.x * 256 + threadIdx.x;   // 4096 = (co,ci) pairs
    int co = i >> 6;
    int ci = i & 63;
    float* dst = wr + (size_t)((co >> 3) * 64 + ci) * WSLICE + (co & 7) * 9;
    const float* src = w + (size_t)co * (CI_ * 9) + ci * 9;
#pragma unroll
    for (int t = 0; t < 9; ++t) dst[t] = src[t];
}

__global__ __launch_bounds__(512, 4) void adder2d_kernel(
    const float* __restrict__ x, const float* __restrict__ wr,
    float* __restrict__ out)
{
    __shared__ __align__(16) float smem[SMEM_WORDS];
    float (*xs)[ROWS][LW] = (float (*)[ROWS][LW])smem;   // phase A
    float (*red)[128][16] = (float (*)[128][16])smem;    // phase B: aliases xs

    const int tid = threadIdx.x;
    const int u   = tid & 15;            // col-pair: pixels at cols 2u, 2u+1
    const int rl  = (tid >> 4) & 7;      // pixel row within block
    const int cig = tid >> 7;            // ci group: 0..3 (uniform per wave)
    const int r0  = blockIdx.x * RG;
    const int co0 = blockIdx.y * COB;
    const int n   = blockIdx.z;

    // wave-uniform group index -> provably scalar w pointer (s_load path)
    const int cigs = __builtin_amdgcn_readfirstlane(cig);
    const float* wrb = wr + (size_t)blockIdx.y * 64 * WSLICE;

    // ---- zero xs once: halo words (0,33) and OOB row slots stay zero ----
    for (int i = tid; i < XS_WORDS / 4; i += 512)
        ((float4*)smem)[i] = float4{0.f, 0.f, 0.f, 0.f};

    f2 acc2[CG];                         // .x = pixel col 2u, .y = col 2u+1
#pragma unroll
    for (int j = 0; j < CG; ++j) acc2[j] = f2{0.f, 0.f};

    const float* xn = x + (size_t)n * CI_ * HW_ * HW_;
    const int pbase = cig * CPG;

    for (int round = 0; round < CI_ / CIC; ++round) {
        const int cc0 = round * CIC;
        __syncthreads();   // protect LDS from previous round's readers
        // ---- stage CIC planes, rows r0-1..r0+8: 1280 float4 units ----
        for (int i = tid; i < CIC * ROWS * (HW_ / 4); i += 512) {
            int plane = i / (ROWS * (HW_ / 4));
            int rem   = i - plane * (ROWS * (HW_ / 4));
            int rr    = rem >> 3;
            int f4    = rem & 7;
            int gr    = r0 - 1 + rr;
            if ((unsigned)gr < HW_) {
                float4 v = ((const float4*)(xn + (size_t)(cc0 + plane) * HW_ * HW_
                                            + gr * HW_))[f4];
                float* dst = &xs[plane][rr][1 + 4 * f4];   // data words 1..32
                dst[0] = v.x; dst[1] = v.y; dst[2] = v.z; dst[3] = v.w;
            }
        }
        __syncthreads();

#pragma unroll 1
        for (int cil = 0; cil < CPG; ++cil) {
            const int pl  = pbase + cil;             // per-thread (LDS path)
            const int cis = cc0 + cigs * CPG + cil;  // uniform (SMEM path)

            // ---- w octet-slice (72 floats) from uniform ptr -> s_load ----
            const float* wu_p = wrb + (size_t)cis * WSLICE;
            float wu[72];
#pragma unroll
            for (int t = 0; t < 72; ++t) wu[t] = wu_p[t];

            // x window: 3 overlapping f2 pairs per row, 12 b32 reads,
            // reused by all 8 co (the amortization)
            f2 xp[3][3];
#pragma unroll
            for (int kh = 0; kh < 3; ++kh) {
                const float* row = &xs[pl][rl + kh][2 * u];
                float a = row[0], b = row[1], c = row[2], d = row[3];
                xp[kh][0] = f2{a, b};
                xp[kh][1] = f2{b, c};
                xp[kh][2] = f2{c, d};
            }

            // packed core: 9 taps x 8 co x {pk_sub, 2x abs-add} = 216 VALU
#pragma unroll
            for (int kh = 0; kh < 3; ++kh)
#pragma unroll
                for (int kw = 0; kw < 3; ++kw) {
                    const int t = kh * 3 + kw;
#pragma unroll
                    for (int j = 0; j < CG; ++j) {
                        const float wjt = wu[j * 9 + t];
                        f2 dv = xp[kh][kw] - f2{wjt, wjt};
                        acc2[j] += __builtin_elementwise_abs(dv);
                    }
                }
        }
    }

    // ---- combine the four ci-group partials (red aliases dead xs) ----
    __syncthreads();   // all xs readers done before overwrite
    if (cig != 0) {
        int t = tid & 127;
#pragma unroll
        for (int j = 0; j < CG; j += 2)
            *(float4*)&red[cig - 1][t][2 * j] =
                float4{acc2[j].x, acc2[j].y, acc2[j + 1].x, acc2[j + 1].y};
    }
    __syncthreads();
    if (cig == 0) {
#pragma unroll
        for (int g = 0; g < 3; ++g)
#pragma unroll
            for (int j = 0; j < CG; j += 2) {
                float4 rv = *(const float4*)&red[g][tid][2 * j];
                acc2[j].x     += rv.x; acc2[j].y     += rv.y;
                acc2[j + 1].x += rv.z; acc2[j + 1].y += rv.w;
            }
        float* op = out + (((size_t)n * CO_ + co0) * HW_ + (r0 + rl)) * HW_ + 2 * u;
#pragma unroll
        for (int j = 0; j < CG; ++j)
            *(float2*)&op[(size_t)j * HW_ * HW_] = float2{-acc2[j].x, -acc2[j].y};
    }
}

extern "C" void kernel_launch(void* const* d_in, const int* in_sizes, int n_in,
                              void* d_out, int out_size, void* d_ws, size_t ws_size,
                              hipStream_t stream) {
    const float* x  = (const float*)d_in[0];
    const float* wp = (const float*)d_in[1];
    float* out      = (float*)d_out;
    float* wr       = (float*)d_ws;   // 256 KiB (proven-safe footprint)

    repack_w<<<dim3(16), 256, 0, stream>>>(wp, wr);
    dim3 grid(HW_ / RG, CO_ / COB, N_);   // (4, 8, 16) = 512 blocks
    adder2d_kernel<<<grid, 512, 0, stream>>>(x, wr, out);
}